// Round 7
// baseline (552.398 us; speedup 1.0000x reference)
//
#include <hip/hip_runtime.h>
#include <hip/hip_bf16.h>
#include <cstdint>

// GatedMultiheadAttention: B=2, N=2048, E=1024, H=16, D=64
// R13 = R10 attn body (53us reference) at 4 waves/block for TLP:
//  - Diagnosis: R10/R11/R12 (three sync structures, two tile shapes) all
//    53-58us, no pipe >40% busy -> latency-bound at ~2 waves/SIMD. The one
//    untouched variable was wave count.
//  - 256 thr / 4 waves x 32 q-rows (block = 128 rows), grid (64,16,2)=2048.
//    LDS 16KB (dbuf) + VGPR ~48 -> 8 blocks x 4 waves ~ 28-32 waves/CU
//    (was ~8). Per-thread staging halves (1 K + 1 V async16).
//  - kt loop fully unrolled: cur/addresses become compile-time (cuts the
//    per-iter address-VALU that the ring variant showed is expensive).
// ws (48MB): weights 0-8, XQ 8-16, XK/XV 16-32 (-> OPp partials + AOB),
// QB 32-40, KB 40-48. d_out: VTB low 8MB, partial3 high 8MB.

#define DEV __device__ __forceinline__
typedef __attribute__((ext_vector_type(8))) short bf16x8;
typedef __attribute__((ext_vector_type(4))) float f32x4;
typedef unsigned short u16;

DEV void async16(const void* g, void* l) {
  __builtin_amdgcn_global_load_lds(
      (const __attribute__((address_space(1))) unsigned int*)g,
      (__attribute__((address_space(3))) unsigned int*)l, 16, 0, 0);
}

DEV u16 bf16_rne(float f) {
  unsigned int u = __builtin_bit_cast(unsigned int, f);
  u += 0x7FFFu + ((u >> 16) & 1u);
  return (u16)(u >> 16);
}

DEV u16 cvt16(float x) {
  __hip_bfloat16 h = __float2bfloat16(x);
  return __builtin_bit_cast(u16, h);
}

// packed RNE f32x2 -> bf16x2 in one VALU op (low = lo, high = hi)
DEV unsigned cvtpk(float lo, float hi) {
  unsigned r;
  asm("v_cvt_pk_bf16_f32 %0, %1, %2" : "=v"(r) : "v"(lo), "v"(hi));
  return r;
}

// ---------------- one fused cast: q,k,v + 4 weights ----------------
__global__ __launch_bounds__(256) void cast_all(
    const float* __restrict__ q, const float* __restrict__ k, const float* __restrict__ v,
    const float* __restrict__ Wq, const float* __restrict__ Wk,
    const float* __restrict__ Wv, const float* __restrict__ Wo,
    u16* __restrict__ XQ, u16* __restrict__ XK, u16* __restrict__ XV,
    u16* __restrict__ WQB, u16* __restrict__ WKB, u16* __restrict__ WVB,
    u16* __restrict__ WOB) {
  int idx = blockIdx.x * 256 + threadIdx.x;  // one 8-elem item each
  const float* src; u16* dst; int i;
  if      (idx <  524288) { src = q;  dst = XQ;  i = idx; }
  else if (idx < 1048576) { src = k;  dst = XK;  i = idx -  524288; }
  else if (idx < 1572864) { src = v;  dst = XV;  i = idx - 1048576; }
  else if (idx < 1703936) { src = Wq; dst = WQB; i = idx - 1572864; }
  else if (idx < 1835008) { src = Wk; dst = WKB; i = idx - 1703936; }
  else if (idx < 1966080) { src = Wv; dst = WVB; i = idx - 1835008; }
  else                    { src = Wo; dst = WOB; i = idx - 1966080; }
  const float4* p = (const float4*)src + (size_t)i * 2;
  float4 a = p[0], b = p[1];
  union { u16 us[8]; uint4 vv; } u;
  u.us[0] = bf16_rne(a.x); u.us[1] = bf16_rne(a.y);
  u.us[2] = bf16_rne(a.z); u.us[3] = bf16_rne(a.w);
  u.us[4] = bf16_rne(b.x); u.us[5] = bf16_rne(b.y);
  u.us[6] = bf16_rne(b.z); u.us[7] = bf16_rne(b.w);
  ((uint4*)dst)[i] = u.vv;
}

// ---------------- fused QKV projection GEMM (768 blocks, 128x128, dbuf) ------
// T1 swizzle: xcd = bx&7 owns bm-stripe xcd*4..+3 for all segs; seg-major,
// bn fastest -> per XCD: A-panels (4bm x 3seg x 256KB) + W-seg L2-resident.
__global__ __launch_bounds__(256, 3) void gemm_qkv(
    const u16* __restrict__ XQ, const u16* __restrict__ XK, const u16* __restrict__ XV,
    const u16* __restrict__ Wb,  // WQ|WK|WV contiguous, 1M elems apart
    const float* __restrict__ bq, const float* __restrict__ bkb, const float* __restrict__ bv,
    const float* __restrict__ gate,
    u16* __restrict__ QB, u16* __restrict__ KB, u16* __restrict__ VTB) {
  __shared__ __attribute__((aligned(16))) u16 As[2][128 * 32];
  __shared__ __attribute__((aligned(16))) u16 Bs[2][128 * 32];
  const int t = threadIdx.x, lane = t & 63, w = t >> 6;
  const int l15 = lane & 15, quad = lane >> 4;
  const int xcd = blockIdx.x & 7, idx = blockIdx.x >> 3;
  const int seg = idx >> 5, r5 = idx & 31;
  const int bm = (xcd << 2) + (r5 >> 3), bn = r5 & 7;
  const int m0 = bm << 7, n0 = bn << 7;
  const u16* A = (seg == 0) ? XQ : (seg == 1) ? XK : XV;
  const u16* W = Wb + (long)seg * 1048576;
  const int wm = (w >> 1) << 6, wn = (w & 1) << 6;
  const int r0 = t >> 2, cc0 = (t & 3) * 8;
  const u16* gA0 = A + (long)(m0 + r0) * 1024 + cc0;
  const u16* gA1 = gA0 + 64 * 1024;
  const u16* gB0 = W + (long)(n0 + r0) * 1024 + cc0;
  const u16* gB1 = gB0 + 64 * 1024;

  async16(gA0, &As[0][t * 8]); async16(gA1, &As[0][(t + 256) * 8]);
  async16(gB0, &Bs[0][t * 8]); async16(gB1, &Bs[0][(t + 256) * 8]);

  f32x4 acc[4][4] = {};
  for (int k0 = 0; k0 < 1024; k0 += 32) {
    const int cur = (k0 >> 5) & 1;
    __syncthreads();
    if (k0 + 32 < 1024) {
      const int kn = k0 + 32, nb = cur ^ 1;
      async16(gA0 + kn, &As[nb][t * 8]); async16(gA1 + kn, &As[nb][(t + 256) * 8]);
      async16(gB0 + kn, &Bs[nb][t * 8]); async16(gB1 + kn, &Bs[nb][(t + 256) * 8]);
    }
    bf16x8 af[4], bfm[4];
#pragma unroll
    for (int i = 0; i < 4; i++)
      af[i] = *(const bf16x8*)&As[cur][(wm + i * 16 + l15) * 32 + quad * 8];
#pragma unroll
    for (int j = 0; j < 4; j++)
      bfm[j] = *(const bf16x8*)&Bs[cur][(wn + j * 16 + l15) * 32 + quad * 8];
#pragma unroll
    for (int i = 0; i < 4; i++)
#pragma unroll
      for (int j = 0; j < 4; j++)
        acc[i][j] = __builtin_amdgcn_mfma_f32_16x16x32_bf16(af[i], bfm[j], acc[i][j], 0, 0, 0);
  }

  if (seg == 2) {  // V: bias + transposed write V^T[(b*1024+col)*2048 + n]
#pragma unroll
    for (int i = 0; i < 4; i++) {
      int token = m0 + wm + i * 16 + quad * 4;
      int bb_ = token >> 11, n = token & 2047;
#pragma unroll
      for (int j = 0; j < 4; j++) {
        int col = n0 + wn + j * 16 + l15;
        float bb = bv[col];
        union { u16 us[4]; uint2 u2; } pk;
#pragma unroll
        for (int r = 0; r < 4; r++) pk.us[r] = bf16_rne(acc[i][j][r] + bb);
        *(uint2*)&VTB[(long)(bb_ * 1024 + col) * 2048 + n] = pk.u2;
      }
    }
  } else {
    const float* bias = seg ? bkb : bq;
    u16* C = seg ? KB : QB;
#pragma unroll
    for (int j = 0; j < 4; j++) {
      int col = n0 + wn + j * 16 + l15;
      float bb = bias[col];
      float scl = 1.f;
      if (seg == 0) {
        float g = gate[col >> 6];
        float sig = 1.f / (1.f + __builtin_amdgcn_exp2f(-g * 1.44269504f));
        scl = sig * 0.125f * 1.44269504f;
      }
#pragma unroll
      for (int i = 0; i < 4; i++) {
        int row = m0 + wm + i * 16 + quad * 4;
#pragma unroll
        for (int r = 0; r < 4; r++)
          C[(long)(row + r) * 1024 + col] = bf16_rne((acc[i][j][r] + bb) * scl);
      }
    }
  }
}

// ---------------- out-proj GEMM: 64x128 tiles, dbuf, fp32 out ----------------
// T1 swizzle: xcd owns bm-stripe xcd*8..+7, bn fastest.
__global__ __launch_bounds__(256, 2) void gemm_out(
    const u16* __restrict__ A, const u16* __restrict__ W,
    const float* __restrict__ bias, float* __restrict__ Cf) {
  __shared__ __attribute__((aligned(16))) u16 As[2][64 * 32];
  __shared__ __attribute__((aligned(16))) u16 Bs[2][128 * 32];
  const int t = threadIdx.x, lane = t & 63, w = t >> 6;
  const int l15 = lane & 15, quad = lane >> 4;
  const int xcd = blockIdx.x & 7, idx = blockIdx.x >> 3;
  const int bm = (xcd << 3) + (idx >> 3), bn = idx & 7;
  const int m0 = bm << 6, n0 = bn << 7;
  const int wm = (w >> 1) << 5, wn = (w & 1) << 6;
  const int r0 = t >> 2, cc0 = (t & 3) * 8;
  const u16* gA = A + (long)(m0 + r0) * 1024 + cc0;
  const u16* gB0 = W + (long)(n0 + r0) * 1024 + cc0;
  const u16* gB1 = gB0 + 64 * 1024;

  async16(gA, &As[0][t * 8]);
  async16(gB0, &Bs[0][t * 8]); async16(gB1, &Bs[0][(t + 256) * 8]);

  f32x4 acc[2][4] = {};
  for (int k0 = 0; k0 < 1024; k0 += 32) {
    const int cur = (k0 >> 5) & 1;
    __syncthreads();
    if (k0 + 32 < 1024) {
      const int kn = k0 + 32, nb = cur ^ 1;
      async16(gA + kn, &As[nb][t * 8]);
      async16(gB0 + kn, &Bs[nb][t * 8]); async16(gB1 + kn, &Bs[nb][(t + 256) * 8]);
    }
    bf16x8 af[2], bfm[4];
#pragma unroll
    for (int i = 0; i < 2; i++)
      af[i] = *(const bf16x8*)&As[cur][(wm + i * 16 + l15) * 32 + quad * 8];
#pragma unroll
    for (int j = 0; j < 4; j++)
      bfm[j] = *(const bf16x8*)&Bs[cur][(wn + j * 16 + l15) * 32 + quad * 8];
#pragma unroll
    for (int i = 0; i < 2; i++)
#pragma unroll
      for (int j = 0; j < 4; j++)
        acc[i][j] = __builtin_amdgcn_mfma_f32_16x16x32_bf16(af[i], bfm[j], acc[i][j], 0, 0, 0);
  }

#pragma unroll
  for (int j = 0; j < 4; j++) {
    int col = n0 + wn + j * 16 + l15;
    float bb = bias[col];
#pragma unroll
    for (int i = 0; i < 2; i++) {
      int row = m0 + wm + i * 16 + quad * 4;
#pragma unroll
      for (int r = 0; r < 4; r++)
        Cf[(long)(row + r) * 1024 + col] = acc[i][j][r] + bb;
    }
  }
}

// ---------------- split-K x4 flash attention, 4 waves x 32 q-rows -----------
// grid (64,16,2) x 256 thr. xcd = bx&7; ksp = xcd>>1, qt = ((xcd&1)<<3)|rr
// (0..15); block owns q-rows qt*128..+127, wave w rows q0+w*32..+31.
// Swapped QK^T: lane (l15,quad) holds q=i*16+l15, keys 8*quad+2r+j == its PV
// A-frag keys -> P packed in-register via v_cvt_pk_bf16_f32, no P LDS.
// Staging: 1 K + 1 V async16 per thread per iter; dbuf + __syncthreads
// (R10's 53us structure). kt loop fully unrolled (static cur/offsets).
__global__ __launch_bounds__(256, 7) void attn_kernel(
    const u16* __restrict__ Q, const u16* __restrict__ Kb,
    const u16* __restrict__ Vt, u16* __restrict__ Op0, u16* __restrict__ Op3,
    float* __restrict__ lp) {
  __shared__ __attribute__((aligned(16))) u16 Ks[2][32 * 64];  // [key][d], 128B rows
  __shared__ __attribute__((aligned(16))) u16 Vs[2][64 * 32];  // [d][key], 64B rows
  const int t = threadIdx.x, lane = t & 63, w = t >> 6;
  const int l15 = lane & 15, quad = lane >> 4;
  const int xcd = blockIdx.x & 7, rr = blockIdx.x >> 3;
  const int ksp = xcd >> 1, qt = ((xcd & 1) << 3) | rr;
  const int h = blockIdx.y, b = blockIdx.z;
  const int q0 = qt * 128, tok0 = b * 2048, key0 = ksp * 512;
  const u16* Kbase = Kb + (long)tok0 * 1024 + h * 64;
  const u16* Vbase = Vt + (long)(b * 1024 + h * 64) * 2048 + key0;

  // loop-invariant Q fragments (B operand; wave rows q0 + w*32 .. +31)
  bf16x8 aq[2][2];
#pragma unroll
  for (int i = 0; i < 2; i++) {
    long row = tok0 + q0 + w * 32 + i * 16 + l15;
#pragma unroll
    for (int ks = 0; ks < 2; ks++)
      aq[i][ks] = *(const bf16x8*)&Q[row * 1024 + h * 64 + ks * 32 + quad * 8];
  }

  // per-thread staging addrs (256 thr cover 2048-elem tiles in 8-elem chunks).
  // K: chunk ^ ((row>>1)&7); V: chunk ^ ((row>>1)&3) -- swizzle on the GLOBAL
  // chunk so the linear global_load_lds destination stays lane-contiguous.
  const int rk = t >> 3, ck = t & 7;
  const int rv = t >> 2, cv = t & 3;
  const u16* kg = Kbase + (long)(key0 + rk) * 1024 + ((ck ^ ((rk >> 1) & 7)) * 8);
  const u16* vg = Vbase + (long)rv * 2048 + ((cv ^ ((rv >> 1) & 3)) * 8);
  u16* ksd = &Ks[0][t * 8];
  u16* vsd = &Vs[0][t * 8];

  auto STAGE = [&](int tk, int bu) {
    async16(kg + (long)tk * 32768, ksd + bu * 2048);  // +32 rows * 1024
    async16(vg + tk * 32, vsd + bu * 2048);           // +32 key-cols
  };

  STAGE(0, 0);

  float l_st[2] = {};   // per-lane partial over this lane's keys
  f32x4 O[2][4] = {};

#pragma unroll
  for (int kt = 0; kt < 16; kt++) {
    const int cur = kt & 1;
    __syncthreads();
    if (kt + 1 < 16) STAGE(kt + 1, cur ^ 1);

    // S^T = K Q^T (exp2 domain): A = K rows 2*l15+j, B = aq.
    f32x4 s[2][2] = {};
    __builtin_amdgcn_s_setprio(1);
#pragma unroll
    for (int ks = 0; ks < 2; ks++) {
      bf16x8 bk_[2];
#pragma unroll
      for (int j = 0; j < 2; j++) {
        int rl = 2 * l15 + j;
        bk_[j] = *(const bf16x8*)&Ks[cur][rl * 64 + (((ks * 4 + quad) ^ (l15 & 7))) * 8];
      }
#pragma unroll
      for (int i = 0; i < 2; i++)
#pragma unroll
        for (int j = 0; j < 2; j++)
          s[i][j] = __builtin_amdgcn_mfma_f32_16x16x32_bf16(bk_[j], aq[i][ks], s[i][j], 0, 0, 0);
    }
    __builtin_amdgcn_s_setprio(0);

    // exp2 + in-register pack via cvt_pk: ap[i] word r = keys (8q+2r, 8q+2r+1)
    bf16x8 ap[2];
#pragma unroll
    for (int i = 0; i < 2; i++) {
      union { unsigned uw[4]; bf16x8 v8; } pw;
#pragma unroll
      for (int r = 0; r < 4; r++) {
        float p0 = __builtin_amdgcn_exp2f(s[i][0][r]);
        float p1 = __builtin_amdgcn_exp2f(s[i][1][r]);
        l_st[i] += p0 + p1;
        pw.uw[r] = cvtpk(p0, p1);
      }
      ap[i] = pw.v8;
    }

    // V fragments from LDS; O += P @ V (single K=32 MFMA pass)
    bf16x8 bv_[4];
#pragma unroll
    for (int dj = 0; dj < 4; dj++) {
      int rl = dj * 16 + l15;
      bv_[dj] = *(const bf16x8*)&Vs[cur][rl * 32 + ((quad ^ ((rl >> 1) & 3))) * 8];
    }
    __builtin_amdgcn_s_setprio(1);
#pragma unroll
    for (int i = 0; i < 2; i++)
#pragma unroll
      for (int dj = 0; dj < 4; dj++)
        O[i][dj] = __builtin_amdgcn_mfma_f32_16x16x32_bf16(ap[i], bv_[dj], O[i][dj], 0, 0, 0);
    __builtin_amdgcn_s_setprio(0);
  }

  // epilogue: l reduced across quads; store O (bf16) + l (f32)
  u16* dst = (ksp == 3) ? Op3 : (Op0 + (long)ksp * 4194304);
#pragma unroll
  for (int i = 0; i < 2; i++) {
    float ls = l_st[i];
    ls += __shfl_xor(ls, 16); ls += __shfl_xor(ls, 32);
    if (quad == 0) {
      long qrow = tok0 + q0 + w * 32 + i * 16 + l15;
      lp[ksp * 65536 + (int)qrow * 16 + h] = ls;
    }
#pragma unroll
    for (int r = 0; r < 4; r++) {
      long row = tok0 + q0 + w * 32 + i * 16 + quad * 4 + r;
#pragma unroll
      for (int dj = 0; dj < 4; dj++)
        dst[row * 1024 + h * 64 + dj * 16 + l15] = cvt16(O[i][dj][r]);
    }
  }
}

// ---------------- merge split-K partials: AO = (O0+..+O3)/(l0+..+l3) --------
// AO aliases partial 0 (per-thread read-before-write, 1:1 map -> safe).
__global__ __launch_bounds__(256) void merge_kernel(
    const u16* __restrict__ Op0, const u16* __restrict__ Op3,
    const float* __restrict__ lp, u16* __restrict__ AO) {
  int idx = blockIdx.x * 256 + threadIdx.x;  // 524288 chunks of 8 elems
  int tok = idx >> 7, rem = idx & 127, h = rem >> 3;
  int li = tok * 16 + h;
  float inv = 1.f / (lp[li] + lp[65536 + li] + lp[131072 + li] + lp[196608 + li]);
  union U { uint4 v; u16 us[8]; };
  U a0, a1, a2, a3, uo;
  a0.v = ((const uint4*)Op0)[idx];
  a1.v = ((const uint4*)Op0)[idx + 524288];
  a2.v = ((const uint4*)Op0)[idx + 1048576];
  a3.v = ((const uint4*)Op3)[idx];
#pragma unroll
  for (int j = 0; j < 8; j++) {
    float f0 = __builtin_bit_cast(float, (unsigned)((unsigned)a0.us[j] << 16));
    float f1 = __builtin_bit_cast(float, (unsigned)((unsigned)a1.us[j] << 16));
    float f2 = __builtin_bit_cast(float, (unsigned)((unsigned)a2.us[j] << 16));
    float f3 = __builtin_bit_cast(float, (unsigned)((unsigned)a3.us[j] << 16));
    uo.us[j] = cvt16((f0 + f1 + f2 + f3) * inv);
  }
  ((uint4*)AO)[idx] = uo.v;
}

extern "C" void kernel_launch(void* const* d_in, const int* in_sizes, int n_in,
                              void* d_out, int out_size, void* d_ws, size_t ws_size,
                              hipStream_t stream) {
  const float* q  = (const float*)d_in[0];
  const float* k  = (const float*)d_in[1];
  const float* v  = (const float*)d_in[2];
  const float* Wq = (const float*)d_in[3];
  const float* bq = (const float*)d_in[4];
  const float* Wk = (const float*)d_in[5];
  const float* bk = (const float*)d_in[6];
  const float* Wv = (const float*)d_in[7];
  const float* bv = (const float*)d_in[8];
  const float* Wo = (const float*)d_in[9];
  const float* bo = (const float*)d_in[10];
  const float* gate = (const float*)d_in[11];
  float* out = (float*)d_out;
  char* ws = (char*)d_ws;

  const size_t MB = 1u << 20;
  u16* WQB = (u16*)(ws + 0 * MB);   // WQ|WK|WV|WO contiguous (2MB each)
  u16* WKB = (u16*)(ws + 2 * MB);
  u16* WVB = (u16*)(ws + 4 * MB);
  u16* WOB = (u16*)(ws + 6 * MB);
  u16* XQ  = (u16*)(ws + 8 * MB);
  u16* XK  = (u16*)(ws + 16 * MB);
  u16* XV  = (u16*)(ws + 24 * MB);
  u16* QB  = (u16*)(ws + 32 * MB);
  u16* KB  = (u16*)(ws + 40 * MB);
  u16* OPp  = (u16*)(ws + 8 * MB);             // partials 0-2 (24MB over dead XQ/XK/XV)
  u16* OPd3 = (u16*)((char*)d_out + 8 * MB);   // partial 3 in d_out's upper half
  float* LP = (float*)(ws + 0 * MB);           // 1MB partial l (over dead WQB)
  u16* AOB  = (u16*)(ws + 8 * MB);             // == partial 0 (merge self-overwrite)
  u16* VTB  = (u16*)d_out;                     // d_out low 8MB as V^T scratch

  cast_all<<<8192, 256, 0, stream>>>(q, k, v, Wq, Wk, Wv, Wo,
                                     XQ, XK, XV, WQB, WKB, WVB, WOB);
  gemm_qkv<<<768, 256, 0, stream>>>(XQ, XK, XV, WQB, bq, bk, bv, gate, QB, KB, VTB);
  attn_kernel<<<dim3(64, 16, 2), 256, 0, stream>>>(QB, KB, VTB, OPp, OPd3, LP);
  merge_kernel<<<2048, 256, 0, stream>>>(OPp, OPd3, LP, AOB);
  gemm_out<<<512, 256, 0, stream>>>(AOB, WOB, bo, out);
}

// Round 8
// 228.002 us; speedup vs baseline: 2.4228x; 2.4228x over previous
//
#include <hip/hip_runtime.h>
#include <hip/hip_bf16.h>
#include <cstdint>

// GatedMultiheadAttention: B=2, N=2048, E=1024, H=16, D=64
// R14 = R13 (4-wave attn blocks) with the register catastrophe fixed:
//  - R13 post-mortem: launch_bounds(256,7)+full unroll -> VGPR 36, total
//    spill (FETCH 450MB/WRITE 873MB scratch traffic), MfmaUtil 3.8%. BUT
//    occupancy hit 66% (vs 25%) -> the 4-wave TLP lever itself works.
//  - Fix: launch_bounds(256,4) (VGPR cap 128; body needs ~48) + plain
//    non-unrolled kt loop (R10's form that measured 48 VGPR).
//  - Geometry unchanged from R13 (passed correctness): 4 waves x 32 q-rows,
//    grid (64,16,2)=2048 blocks = 8/CU, LDS 16KB dbuf, 1K+1V stage/thread.
// ws (48MB): weights 0-8, XQ 8-16, XK/XV 16-32 (-> OPp partials + AOB),
// QB 32-40, KB 40-48. d_out: VTB low 8MB, partial3 high 8MB.

#define DEV __device__ __forceinline__
typedef __attribute__((ext_vector_type(8))) short bf16x8;
typedef __attribute__((ext_vector_type(4))) float f32x4;
typedef unsigned short u16;

DEV void async16(const void* g, void* l) {
  __builtin_amdgcn_global_load_lds(
      (const __attribute__((address_space(1))) unsigned int*)g,
      (__attribute__((address_space(3))) unsigned int*)l, 16, 0, 0);
}

DEV u16 bf16_rne(float f) {
  unsigned int u = __builtin_bit_cast(unsigned int, f);
  u += 0x7FFFu + ((u >> 16) & 1u);
  return (u16)(u >> 16);
}

DEV u16 cvt16(float x) {
  __hip_bfloat16 h = __float2bfloat16(x);
  return __builtin_bit_cast(u16, h);
}

// packed RNE f32x2 -> bf16x2 in one VALU op (low = lo, high = hi)
DEV unsigned cvtpk(float lo, float hi) {
  unsigned r;
  asm("v_cvt_pk_bf16_f32 %0, %1, %2" : "=v"(r) : "v"(lo), "v"(hi));
  return r;
}

// ---------------- one fused cast: q,k,v + 4 weights ----------------
__global__ __launch_bounds__(256) void cast_all(
    const float* __restrict__ q, const float* __restrict__ k, const float* __restrict__ v,
    const float* __restrict__ Wq, const float* __restrict__ Wk,
    const float* __restrict__ Wv, const float* __restrict__ Wo,
    u16* __restrict__ XQ, u16* __restrict__ XK, u16* __restrict__ XV,
    u16* __restrict__ WQB, u16* __restrict__ WKB, u16* __restrict__ WVB,
    u16* __restrict__ WOB) {
  int idx = blockIdx.x * 256 + threadIdx.x;  // one 8-elem item each
  const float* src; u16* dst; int i;
  if      (idx <  524288) { src = q;  dst = XQ;  i = idx; }
  else if (idx < 1048576) { src = k;  dst = XK;  i = idx -  524288; }
  else if (idx < 1572864) { src = v;  dst = XV;  i = idx - 1048576; }
  else if (idx < 1703936) { src = Wq; dst = WQB; i = idx - 1572864; }
  else if (idx < 1835008) { src = Wk; dst = WKB; i = idx - 1703936; }
  else if (idx < 1966080) { src = Wv; dst = WVB; i = idx - 1835008; }
  else                    { src = Wo; dst = WOB; i = idx - 1966080; }
  const float4* p = (const float4*)src + (size_t)i * 2;
  float4 a = p[0], b = p[1];
  union { u16 us[8]; uint4 vv; } u;
  u.us[0] = bf16_rne(a.x); u.us[1] = bf16_rne(a.y);
  u.us[2] = bf16_rne(a.z); u.us[3] = bf16_rne(a.w);
  u.us[4] = bf16_rne(b.x); u.us[5] = bf16_rne(b.y);
  u.us[6] = bf16_rne(b.z); u.us[7] = bf16_rne(b.w);
  ((uint4*)dst)[i] = u.vv;
}

// ---------------- fused QKV projection GEMM (768 blocks, 128x128, dbuf) ------
// T1 swizzle: xcd = bx&7 owns bm-stripe xcd*4..+3 for all segs; seg-major,
// bn fastest -> per XCD: A-panels (4bm x 3seg x 256KB) + W-seg L2-resident.
__global__ __launch_bounds__(256, 3) void gemm_qkv(
    const u16* __restrict__ XQ, const u16* __restrict__ XK, const u16* __restrict__ XV,
    const u16* __restrict__ Wb,  // WQ|WK|WV contiguous, 1M elems apart
    const float* __restrict__ bq, const float* __restrict__ bkb, const float* __restrict__ bv,
    const float* __restrict__ gate,
    u16* __restrict__ QB, u16* __restrict__ KB, u16* __restrict__ VTB) {
  __shared__ __attribute__((aligned(16))) u16 As[2][128 * 32];
  __shared__ __attribute__((aligned(16))) u16 Bs[2][128 * 32];
  const int t = threadIdx.x, lane = t & 63, w = t >> 6;
  const int l15 = lane & 15, quad = lane >> 4;
  const int xcd = blockIdx.x & 7, idx = blockIdx.x >> 3;
  const int seg = idx >> 5, r5 = idx & 31;
  const int bm = (xcd << 2) + (r5 >> 3), bn = r5 & 7;
  const int m0 = bm << 7, n0 = bn << 7;
  const u16* A = (seg == 0) ? XQ : (seg == 1) ? XK : XV;
  const u16* W = Wb + (long)seg * 1048576;
  const int wm = (w >> 1) << 6, wn = (w & 1) << 6;
  const int r0 = t >> 2, cc0 = (t & 3) * 8;
  const u16* gA0 = A + (long)(m0 + r0) * 1024 + cc0;
  const u16* gA1 = gA0 + 64 * 1024;
  const u16* gB0 = W + (long)(n0 + r0) * 1024 + cc0;
  const u16* gB1 = gB0 + 64 * 1024;

  async16(gA0, &As[0][t * 8]); async16(gA1, &As[0][(t + 256) * 8]);
  async16(gB0, &Bs[0][t * 8]); async16(gB1, &Bs[0][(t + 256) * 8]);

  f32x4 acc[4][4] = {};
  for (int k0 = 0; k0 < 1024; k0 += 32) {
    const int cur = (k0 >> 5) & 1;
    __syncthreads();
    if (k0 + 32 < 1024) {
      const int kn = k0 + 32, nb = cur ^ 1;
      async16(gA0 + kn, &As[nb][t * 8]); async16(gA1 + kn, &As[nb][(t + 256) * 8]);
      async16(gB0 + kn, &Bs[nb][t * 8]); async16(gB1 + kn, &Bs[nb][(t + 256) * 8]);
    }
    bf16x8 af[4], bfm[4];
#pragma unroll
    for (int i = 0; i < 4; i++)
      af[i] = *(const bf16x8*)&As[cur][(wm + i * 16 + l15) * 32 + quad * 8];
#pragma unroll
    for (int j = 0; j < 4; j++)
      bfm[j] = *(const bf16x8*)&Bs[cur][(wn + j * 16 + l15) * 32 + quad * 8];
#pragma unroll
    for (int i = 0; i < 4; i++)
#pragma unroll
      for (int j = 0; j < 4; j++)
        acc[i][j] = __builtin_amdgcn_mfma_f32_16x16x32_bf16(af[i], bfm[j], acc[i][j], 0, 0, 0);
  }

  if (seg == 2) {  // V: bias + transposed write V^T[(b*1024+col)*2048 + n]
#pragma unroll
    for (int i = 0; i < 4; i++) {
      int token = m0 + wm + i * 16 + quad * 4;
      int bb_ = token >> 11, n = token & 2047;
#pragma unroll
      for (int j = 0; j < 4; j++) {
        int col = n0 + wn + j * 16 + l15;
        float bb = bv[col];
        union { u16 us[4]; uint2 u2; } pk;
#pragma unroll
        for (int r = 0; r < 4; r++) pk.us[r] = bf16_rne(acc[i][j][r] + bb);
        *(uint2*)&VTB[(long)(bb_ * 1024 + col) * 2048 + n] = pk.u2;
      }
    }
  } else {
    const float* bias = seg ? bkb : bq;
    u16* C = seg ? KB : QB;
#pragma unroll
    for (int j = 0; j < 4; j++) {
      int col = n0 + wn + j * 16 + l15;
      float bb = bias[col];
      float scl = 1.f;
      if (seg == 0) {
        float g = gate[col >> 6];
        float sig = 1.f / (1.f + __builtin_amdgcn_exp2f(-g * 1.44269504f));
        scl = sig * 0.125f * 1.44269504f;
      }
#pragma unroll
      for (int i = 0; i < 4; i++) {
        int row = m0 + wm + i * 16 + quad * 4;
#pragma unroll
        for (int r = 0; r < 4; r++)
          C[(long)(row + r) * 1024 + col] = bf16_rne((acc[i][j][r] + bb) * scl);
      }
    }
  }
}

// ---------------- out-proj GEMM: 64x128 tiles, dbuf, fp32 out ----------------
// T1 swizzle: xcd owns bm-stripe xcd*8..+7, bn fastest.
__global__ __launch_bounds__(256, 2) void gemm_out(
    const u16* __restrict__ A, const u16* __restrict__ W,
    const float* __restrict__ bias, float* __restrict__ Cf) {
  __shared__ __attribute__((aligned(16))) u16 As[2][64 * 32];
  __shared__ __attribute__((aligned(16))) u16 Bs[2][128 * 32];
  const int t = threadIdx.x, lane = t & 63, w = t >> 6;
  const int l15 = lane & 15, quad = lane >> 4;
  const int xcd = blockIdx.x & 7, idx = blockIdx.x >> 3;
  const int bm = (xcd << 3) + (idx >> 3), bn = idx & 7;
  const int m0 = bm << 6, n0 = bn << 7;
  const int wm = (w >> 1) << 5, wn = (w & 1) << 6;
  const int r0 = t >> 2, cc0 = (t & 3) * 8;
  const u16* gA = A + (long)(m0 + r0) * 1024 + cc0;
  const u16* gB0 = W + (long)(n0 + r0) * 1024 + cc0;
  const u16* gB1 = gB0 + 64 * 1024;

  async16(gA, &As[0][t * 8]);
  async16(gB0, &Bs[0][t * 8]); async16(gB1, &Bs[0][(t + 256) * 8]);

  f32x4 acc[2][4] = {};
  for (int k0 = 0; k0 < 1024; k0 += 32) {
    const int cur = (k0 >> 5) & 1;
    __syncthreads();
    if (k0 + 32 < 1024) {
      const int kn = k0 + 32, nb = cur ^ 1;
      async16(gA + kn, &As[nb][t * 8]);
      async16(gB0 + kn, &Bs[nb][t * 8]); async16(gB1 + kn, &Bs[nb][(t + 256) * 8]);
    }
    bf16x8 af[2], bfm[4];
#pragma unroll
    for (int i = 0; i < 2; i++)
      af[i] = *(const bf16x8*)&As[cur][(wm + i * 16 + l15) * 32 + quad * 8];
#pragma unroll
    for (int j = 0; j < 4; j++)
      bfm[j] = *(const bf16x8*)&Bs[cur][(wn + j * 16 + l15) * 32 + quad * 8];
#pragma unroll
    for (int i = 0; i < 2; i++)
#pragma unroll
      for (int j = 0; j < 4; j++)
        acc[i][j] = __builtin_amdgcn_mfma_f32_16x16x32_bf16(af[i], bfm[j], acc[i][j], 0, 0, 0);
  }

#pragma unroll
  for (int j = 0; j < 4; j++) {
    int col = n0 + wn + j * 16 + l15;
    float bb = bias[col];
#pragma unroll
    for (int i = 0; i < 2; i++) {
      int row = m0 + wm + i * 16 + quad * 4;
#pragma unroll
      for (int r = 0; r < 4; r++)
        Cf[(long)(row + r) * 1024 + col] = acc[i][j][r] + bb;
    }
  }
}

// ---------------- split-K x4 flash attention, 4 waves x 32 q-rows -----------
// grid (64,16,2) x 256 thr. xcd = bx&7; ksp = xcd>>1, qt = ((xcd&1)<<3)|rr
// (0..15); block owns q-rows qt*128..+127, wave w rows q0+w*32..+31.
// Swapped QK^T: lane (l15,quad) holds q=i*16+l15, keys 8*quad+2r+j == its PV
// A-frag keys -> P packed in-register via v_cvt_pk_bf16_f32, no P LDS.
// Staging: 1 K + 1 V async16 per thread per iter; dbuf + __syncthreads.
// launch_bounds(256,4): VGPR cap 128, body ~48 -> no spill, 8 waves/SIMD HW
// cap; occupancy limited by grid (8 blocks/CU = 32 waves/CU demand).
__global__ __launch_bounds__(256, 4) void attn_kernel(
    const u16* __restrict__ Q, const u16* __restrict__ Kb,
    const u16* __restrict__ Vt, u16* __restrict__ Op0, u16* __restrict__ Op3,
    float* __restrict__ lp) {
  __shared__ __attribute__((aligned(16))) u16 Ks[2][32 * 64];  // [key][d], 128B rows
  __shared__ __attribute__((aligned(16))) u16 Vs[2][64 * 32];  // [d][key], 64B rows
  const int t = threadIdx.x, lane = t & 63, w = t >> 6;
  const int l15 = lane & 15, quad = lane >> 4;
  const int xcd = blockIdx.x & 7, rr = blockIdx.x >> 3;
  const int ksp = xcd >> 1, qt = ((xcd & 1) << 3) | rr;
  const int h = blockIdx.y, b = blockIdx.z;
  const int q0 = qt * 128, tok0 = b * 2048, key0 = ksp * 512;
  const u16* Kbase = Kb + (long)tok0 * 1024 + h * 64;
  const u16* Vbase = Vt + (long)(b * 1024 + h * 64) * 2048 + key0;

  // loop-invariant Q fragments (B operand; wave rows q0 + w*32 .. +31)
  bf16x8 aq[2][2];
#pragma unroll
  for (int i = 0; i < 2; i++) {
    long row = tok0 + q0 + w * 32 + i * 16 + l15;
#pragma unroll
    for (int ks = 0; ks < 2; ks++)
      aq[i][ks] = *(const bf16x8*)&Q[row * 1024 + h * 64 + ks * 32 + quad * 8];
  }

  // per-thread staging addrs (256 thr cover 2048-elem tiles in 8-elem chunks).
  // K: chunk ^ ((row>>1)&7); V: chunk ^ ((row>>1)&3) -- swizzle on the GLOBAL
  // chunk so the linear global_load_lds destination stays lane-contiguous.
  const int rk = t >> 3, ck = t & 7;
  const int rv = t >> 2, cv = t & 3;
  const u16* kg = Kbase + (long)(key0 + rk) * 1024 + ((ck ^ ((rk >> 1) & 7)) * 8);
  const u16* vg = Vbase + (long)rv * 2048 + ((cv ^ ((rv >> 1) & 3)) * 8);
  u16* ksd = &Ks[0][t * 8];
  u16* vsd = &Vs[0][t * 8];

  auto STAGE = [&](int tk, int bu) {
    async16(kg + (long)tk * 32768, ksd + bu * 2048);  // +32 rows * 1024
    async16(vg + tk * 32, vsd + bu * 2048);           // +32 key-cols
  };

  STAGE(0, 0);

  float l_st[2] = {};   // per-lane partial over this lane's keys
  f32x4 O[2][4] = {};

  for (int kt = 0; kt < 16; kt++) {
    const int cur = kt & 1;
    __syncthreads();
    if (kt + 1 < 16) STAGE(kt + 1, cur ^ 1);

    // S^T = K Q^T (exp2 domain): A = K rows 2*l15+j, B = aq.
    f32x4 s[2][2] = {};
    __builtin_amdgcn_s_setprio(1);
#pragma unroll
    for (int ks = 0; ks < 2; ks++) {
      bf16x8 bk_[2];
#pragma unroll
      for (int j = 0; j < 2; j++) {
        int rl = 2 * l15 + j;
        bk_[j] = *(const bf16x8*)&Ks[cur][rl * 64 + (((ks * 4 + quad) ^ (l15 & 7))) * 8];
      }
#pragma unroll
      for (int i = 0; i < 2; i++)
#pragma unroll
        for (int j = 0; j < 2; j++)
          s[i][j] = __builtin_amdgcn_mfma_f32_16x16x32_bf16(bk_[j], aq[i][ks], s[i][j], 0, 0, 0);
    }
    __builtin_amdgcn_s_setprio(0);

    // exp2 + in-register pack via cvt_pk: ap[i] word r = keys (8q+2r, 8q+2r+1)
    bf16x8 ap[2];
#pragma unroll
    for (int i = 0; i < 2; i++) {
      union { unsigned uw[4]; bf16x8 v8; } pw;
#pragma unroll
      for (int r = 0; r < 4; r++) {
        float p0 = __builtin_amdgcn_exp2f(s[i][0][r]);
        float p1 = __builtin_amdgcn_exp2f(s[i][1][r]);
        l_st[i] += p0 + p1;
        pw.uw[r] = cvtpk(p0, p1);
      }
      ap[i] = pw.v8;
    }

    // V fragments from LDS; O += P @ V (single K=32 MFMA pass)
    bf16x8 bv_[4];
#pragma unroll
    for (int dj = 0; dj < 4; dj++) {
      int rl = dj * 16 + l15;
      bv_[dj] = *(const bf16x8*)&Vs[cur][rl * 32 + ((quad ^ ((rl >> 1) & 3))) * 8];
    }
    __builtin_amdgcn_s_setprio(1);
#pragma unroll
    for (int i = 0; i < 2; i++)
#pragma unroll
      for (int dj = 0; dj < 4; dj++)
        O[i][dj] = __builtin_amdgcn_mfma_f32_16x16x32_bf16(ap[i], bv_[dj], O[i][dj], 0, 0, 0);
    __builtin_amdgcn_s_setprio(0);
  }

  // epilogue: l reduced across quads; store O (bf16) + l (f32)
  u16* dst = (ksp == 3) ? Op3 : (Op0 + (long)ksp * 4194304);
#pragma unroll
  for (int i = 0; i < 2; i++) {
    float ls = l_st[i];
    ls += __shfl_xor(ls, 16); ls += __shfl_xor(ls, 32);
    if (quad == 0) {
      long qrow = tok0 + q0 + w * 32 + i * 16 + l15;
      lp[ksp * 65536 + (int)qrow * 16 + h] = ls;
    }
#pragma unroll
    for (int r = 0; r < 4; r++) {
      long row = tok0 + q0 + w * 32 + i * 16 + quad * 4 + r;
#pragma unroll
      for (int dj = 0; dj < 4; dj++)
        dst[row * 1024 + h * 64 + dj * 16 + l15] = cvt16(O[i][dj][r]);
    }
  }
}

// ---------------- merge split-K partials: AO = (O0+..+O3)/(l0+..+l3) --------
// AO aliases partial 0 (per-thread read-before-write, 1:1 map -> safe).
__global__ __launch_bounds__(256) void merge_kernel(
    const u16* __restrict__ Op0, const u16* __restrict__ Op3,
    const float* __restrict__ lp, u16* __restrict__ AO) {
  int idx = blockIdx.x * 256 + threadIdx.x;  // 524288 chunks of 8 elems
  int tok = idx >> 7, rem = idx & 127, h = rem >> 3;
  int li = tok * 16 + h;
  float inv = 1.f / (lp[li] + lp[65536 + li] + lp[131072 + li] + lp[196608 + li]);
  union U { uint4 v; u16 us[8]; };
  U a0, a1, a2, a3, uo;
  a0.v = ((const uint4*)Op0)[idx];
  a1.v = ((const uint4*)Op0)[idx + 524288];
  a2.v = ((const uint4*)Op0)[idx + 1048576];
  a3.v = ((const uint4*)Op3)[idx];
#pragma unroll
  for (int j = 0; j < 8; j++) {
    float f0 = __builtin_bit_cast(float, (unsigned)((unsigned)a0.us[j] << 16));
    float f1 = __builtin_bit_cast(float, (unsigned)((unsigned)a1.us[j] << 16));
    float f2 = __builtin_bit_cast(float, (unsigned)((unsigned)a2.us[j] << 16));
    float f3 = __builtin_bit_cast(float, (unsigned)((unsigned)a3.us[j] << 16));
    uo.us[j] = cvt16((f0 + f1 + f2 + f3) * inv);
  }
  ((uint4*)AO)[idx] = uo.v;
}

extern "C" void kernel_launch(void* const* d_in, const int* in_sizes, int n_in,
                              void* d_out, int out_size, void* d_ws, size_t ws_size,
                              hipStream_t stream) {
  const float* q  = (const float*)d_in[0];
  const float* k  = (const float*)d_in[1];
  const float* v  = (const float*)d_in[2];
  const float* Wq = (const float*)d_in[3];
  const float* bq = (const float*)d_in[4];
  const float* Wk = (const float*)d_in[5];
  const float* bk = (const float*)d_in[6];
  const float* Wv = (const float*)d_in[7];
  const float* bv = (const float*)d_in[8];
  const float* Wo = (const float*)d_in[9];
  const float* bo = (const float*)d_in[10];
  const float* gate = (const float*)d_in[11];
  float* out = (float*)d_out;
  char* ws = (char*)d_ws;

  const size_t MB = 1u << 20;
  u16* WQB = (u16*)(ws + 0 * MB);   // WQ|WK|WV|WO contiguous (2MB each)
  u16* WKB = (u16*)(ws + 2 * MB);
  u16* WVB = (u16*)(ws + 4 * MB);
  u16* WOB = (u16*)(ws + 6 * MB);
  u16* XQ  = (u16*)(ws + 8 * MB);
  u16* XK  = (u16*)(ws + 16 * MB);
  u16* XV  = (u16*)(ws + 24 * MB);
  u16* QB  = (u16*)(ws + 32 * MB);
  u16* KB  = (u16*)(ws + 40 * MB);
  u16* OPp  = (u16*)(ws + 8 * MB);             // partials 0-2 (24MB over dead XQ/XK/XV)
  u16* OPd3 = (u16*)((char*)d_out + 8 * MB);   // partial 3 in d_out's upper half
  float* LP = (float*)(ws + 0 * MB);           // 1MB partial l (over dead WQB)
  u16* AOB  = (u16*)(ws + 8 * MB);             // == partial 0 (merge self-overwrite)
  u16* VTB  = (u16*)d_out;                     // d_out low 8MB as V^T scratch

  cast_all<<<8192, 256, 0, stream>>>(q, k, v, Wq, Wk, Wv, Wo,
                                     XQ, XK, XV, WQB, WKB, WVB, WOB);
  gemm_qkv<<<768, 256, 0, stream>>>(XQ, XK, XV, WQB, bq, bk, bv, gate, QB, KB, VTB);
  attn_kernel<<<dim3(64, 16, 2), 256, 0, stream>>>(QB, KB, VTB, OPp, OPd3, LP);
  merge_kernel<<<2048, 256, 0, stream>>>(OPp, OPd3, LP, AOB);
  gemm_out<<<512, 256, 0, stream>>>(AOB, WOB, bo, out);
}

// Round 9
// 227.148 us; speedup vs baseline: 2.4319x; 1.0038x over previous
//
#include <hip/hip_runtime.h>
#include <hip/hip_bf16.h>
#include <cstdint>

// GatedMultiheadAttention: B=2, N=2048, E=1024, H=16, D=64
// R15 = R14 (attn 44us, verified) + non-attn pipeline work. total-attn has
// been ~180us across ALL rounds -> attn is no longer the bottleneck.
//  - gemm_qkv: A-operand reg-staged DIRECTLY from fp32 q/k/v (float4x2 ->
//    bf16_rne -> ds_write_b128), T14 issue-early/write-late across the dbuf
//    barrier. Kills cast_all's X portion (72MB traffic + a serialization).
//  - cast shrinks to weights-only (cast_w, 2048 blocks, ~6us).
//  - gemm_out: 64x64 tiles -> grid 1024 (4 blocks/CU, 16 waves/CU vs 8),
//    LDS 16KB. Same frag algebra, acc[2][2].
//  - attn + merge unchanged from R14.
// ws (48MB): weights 0-8 (LP 1MB overlays dead WQB), OPp partials 0-2 at
// 8-32MB, QB 32-40, KB 40-48. d_out: VTB low 8MB, partial3 high 8MB.

#define DEV __device__ __forceinline__
typedef __attribute__((ext_vector_type(8))) short bf16x8;
typedef __attribute__((ext_vector_type(4))) float f32x4;
typedef unsigned short u16;

DEV void async16(const void* g, void* l) {
  __builtin_amdgcn_global_load_lds(
      (const __attribute__((address_space(1))) unsigned int*)g,
      (__attribute__((address_space(3))) unsigned int*)l, 16, 0, 0);
}

DEV u16 bf16_rne(float f) {
  unsigned int u = __builtin_bit_cast(unsigned int, f);
  u += 0x7FFFu + ((u >> 16) & 1u);
  return (u16)(u >> 16);
}

DEV u16 cvt16(float x) {
  __hip_bfloat16 h = __float2bfloat16(x);
  return __builtin_bit_cast(u16, h);
}

// packed RNE f32x2 -> bf16x2 in one VALU op (low = lo, high = hi)
DEV unsigned cvtpk(float lo, float hi) {
  unsigned r;
  asm("v_cvt_pk_bf16_f32 %0, %1, %2" : "=v"(r) : "v"(lo), "v"(hi));
  return r;
}

DEV uint4 cvt8(float4 a, float4 b) {
  union { u16 us[8]; uint4 v; } u;
  u.us[0] = bf16_rne(a.x); u.us[1] = bf16_rne(a.y);
  u.us[2] = bf16_rne(a.z); u.us[3] = bf16_rne(a.w);
  u.us[4] = bf16_rne(b.x); u.us[5] = bf16_rne(b.y);
  u.us[6] = bf16_rne(b.z); u.us[7] = bf16_rne(b.w);
  return u.v;
}

// ---------------- weights-only cast (X cast folded into gemm_qkv) ----------
__global__ __launch_bounds__(256) void cast_w(
    const float* __restrict__ Wq, const float* __restrict__ Wk,
    const float* __restrict__ Wv, const float* __restrict__ Wo,
    u16* __restrict__ WQB, u16* __restrict__ WKB, u16* __restrict__ WVB,
    u16* __restrict__ WOB) {
  int idx = blockIdx.x * 256 + threadIdx.x;  // 524288 8-elem items
  const float* src; u16* dst; int i;
  if      (idx < 131072) { src = Wq; dst = WQB; i = idx; }
  else if (idx < 262144) { src = Wk; dst = WKB; i = idx - 131072; }
  else if (idx < 393216) { src = Wv; dst = WVB; i = idx - 262144; }
  else                   { src = Wo; dst = WOB; i = idx - 393216; }
  const float4* p = (const float4*)src + (size_t)i * 2;
  ((uint4*)dst)[i] = cvt8(p[0], p[1]);
}

// ---------------- fused QKV projection GEMM (768 blocks, 128x128, dbuf) ------
// A-operand: fp32 global -> regs -> bf16 ds_write (fused cast). B: bf16 via
// global_load_lds. T1 swizzle: xcd owns bm-stripe xcd*4..+3, seg-major,
// bn fastest.
__global__ __launch_bounds__(256, 3) void gemm_qkv(
    const float* __restrict__ Xq, const float* __restrict__ Xk, const float* __restrict__ Xv,
    const u16* __restrict__ Wb,  // WQ|WK|WV contiguous, 1M elems apart
    const float* __restrict__ bq, const float* __restrict__ bkb, const float* __restrict__ bv,
    const float* __restrict__ gate,
    u16* __restrict__ QB, u16* __restrict__ KB, u16* __restrict__ VTB) {
  __shared__ __attribute__((aligned(16))) u16 As[2][128 * 32];
  __shared__ __attribute__((aligned(16))) u16 Bs[2][128 * 32];
  const int t = threadIdx.x, lane = t & 63, w = t >> 6;
  const int l15 = lane & 15, quad = lane >> 4;
  const int xcd = blockIdx.x & 7, idx = blockIdx.x >> 3;
  const int seg = idx >> 5, r5 = idx & 31;
  const int bm = (xcd << 2) + (r5 >> 3), bn = r5 & 7;
  const int m0 = bm << 7, n0 = bn << 7;
  const float* A = (seg == 0) ? Xq : (seg == 1) ? Xk : Xv;
  const u16* W = Wb + (long)seg * 1048576;
  const int wm = (w >> 1) << 6, wn = (w & 1) << 6;
  const int r0 = t >> 2, cc0 = (t & 3) * 8;
  const float* gA0 = A + (long)(m0 + r0) * 1024 + cc0;
  const float* gA1 = gA0 + 64 * 1024;
  const u16* gB0 = W + (long)(n0 + r0) * 1024 + cc0;
  const u16* gB1 = gB0 + 64 * 1024;

  float4 ra0, ra1, ra2, ra3;  // in-flight A chunk (2 rows x 8 cols fp32)
  auto LOADA = [&](int ko) {
    const float4* p0 = (const float4*)(gA0 + ko);
    const float4* p1 = (const float4*)(gA1 + ko);
    ra0 = p0[0]; ra1 = p0[1]; ra2 = p1[0]; ra3 = p1[1];
  };
  auto WRITEA = [&](int nb) {
    *(uint4*)&As[nb][t * 8] = cvt8(ra0, ra1);
    *(uint4*)&As[nb][(t + 256) * 8] = cvt8(ra2, ra3);
  };

  LOADA(0);
  async16(gB0, &Bs[0][t * 8]); async16(gB1, &Bs[0][(t + 256) * 8]);
  WRITEA(0);
  LOADA(32);  // k=32 rides until next iter's WRITEA

  f32x4 acc[4][4] = {};
  for (int k0 = 0; k0 < 1024; k0 += 32) {
    const int cur = (k0 >> 5) & 1;
    __syncthreads();  // prev readers of buf cur^1 done; cur's writes visible
    if (k0 + 32 < 1024) {
      const int kn = k0 + 32, nb = cur ^ 1;
      WRITEA(nb);  // regs loaded one iter ago (latency covered)
      async16(gB0 + kn, &Bs[nb][t * 8]); async16(gB1 + kn, &Bs[nb][(t + 256) * 8]);
      if (k0 + 64 < 1024) LOADA(k0 + 64);
    }
    bf16x8 af[4], bfm[4];
#pragma unroll
    for (int i = 0; i < 4; i++)
      af[i] = *(const bf16x8*)&As[cur][(wm + i * 16 + l15) * 32 + quad * 8];
#pragma unroll
    for (int j = 0; j < 4; j++)
      bfm[j] = *(const bf16x8*)&Bs[cur][(wn + j * 16 + l15) * 32 + quad * 8];
#pragma unroll
    for (int i = 0; i < 4; i++)
#pragma unroll
      for (int j = 0; j < 4; j++)
        acc[i][j] = __builtin_amdgcn_mfma_f32_16x16x32_bf16(af[i], bfm[j], acc[i][j], 0, 0, 0);
  }

  if (seg == 2) {  // V: bias + transposed write V^T[(b*1024+col)*2048 + n]
#pragma unroll
    for (int i = 0; i < 4; i++) {
      int token = m0 + wm + i * 16 + quad * 4;
      int bb_ = token >> 11, n = token & 2047;
#pragma unroll
      for (int j = 0; j < 4; j++) {
        int col = n0 + wn + j * 16 + l15;
        float bb = bv[col];
        union { u16 us[4]; uint2 u2; } pk;
#pragma unroll
        for (int r = 0; r < 4; r++) pk.us[r] = bf16_rne(acc[i][j][r] + bb);
        *(uint2*)&VTB[(long)(bb_ * 1024 + col) * 2048 + n] = pk.u2;
      }
    }
  } else {
    const float* bias = seg ? bkb : bq;
    u16* C = seg ? KB : QB;
#pragma unroll
    for (int j = 0; j < 4; j++) {
      int col = n0 + wn + j * 16 + l15;
      float bb = bias[col];
      float scl = 1.f;
      if (seg == 0) {
        float g = gate[col >> 6];
        float sig = 1.f / (1.f + __builtin_amdgcn_exp2f(-g * 1.44269504f));
        scl = sig * 0.125f * 1.44269504f;
      }
#pragma unroll
      for (int i = 0; i < 4; i++) {
        int row = m0 + wm + i * 16 + quad * 4;
#pragma unroll
        for (int r = 0; r < 4; r++)
          C[(long)(row + r) * 1024 + col] = bf16_rne((acc[i][j][r] + bb) * scl);
      }
    }
  }
}

// ---------------- out-proj GEMM: 64x64 tiles, dbuf, fp32 out ----------------
// grid 1024 = 4 blocks/CU (was 512 = 2/CU, grid-starved at 8 waves/CU).
// T1 swizzle: xcd owns bm-stripe xcd*8..+7, bn fastest.
__global__ __launch_bounds__(256, 4) void gemm_out(
    const u16* __restrict__ A, const u16* __restrict__ W,
    const float* __restrict__ bias, float* __restrict__ Cf) {
  __shared__ __attribute__((aligned(16))) u16 As[2][64 * 32];
  __shared__ __attribute__((aligned(16))) u16 Bs[2][64 * 32];
  const int t = threadIdx.x, lane = t & 63, w = t >> 6;
  const int l15 = lane & 15, quad = lane >> 4;
  const int xcd = blockIdx.x & 7, idx = blockIdx.x >> 3;
  const int bm = (xcd << 3) + (idx >> 4), bn = idx & 15;
  const int m0 = bm << 6, n0 = bn << 6;
  const int wm = (w >> 1) << 5, wn = (w & 1) << 5;
  const int r0 = t >> 2, cc0 = (t & 3) * 8;
  const u16* gA = A + (long)(m0 + r0) * 1024 + cc0;
  const u16* gB = W + (long)(n0 + r0) * 1024 + cc0;

  async16(gA, &As[0][t * 8]);
  async16(gB, &Bs[0][t * 8]);

  f32x4 acc[2][2] = {};
  for (int k0 = 0; k0 < 1024; k0 += 32) {
    const int cur = (k0 >> 5) & 1;
    __syncthreads();
    if (k0 + 32 < 1024) {
      const int kn = k0 + 32, nb = cur ^ 1;
      async16(gA + kn, &As[nb][t * 8]);
      async16(gB + kn, &Bs[nb][t * 8]);
    }
    bf16x8 af[2], bfm[2];
#pragma unroll
    for (int i = 0; i < 2; i++)
      af[i] = *(const bf16x8*)&As[cur][(wm + i * 16 + l15) * 32 + quad * 8];
#pragma unroll
    for (int j = 0; j < 2; j++)
      bfm[j] = *(const bf16x8*)&Bs[cur][(wn + j * 16 + l15) * 32 + quad * 8];
#pragma unroll
    for (int i = 0; i < 2; i++)
#pragma unroll
      for (int j = 0; j < 2; j++)
        acc[i][j] = __builtin_amdgcn_mfma_f32_16x16x32_bf16(af[i], bfm[j], acc[i][j], 0, 0, 0);
  }

#pragma unroll
  for (int j = 0; j < 2; j++) {
    int col = n0 + wn + j * 16 + l15;
    float bb = bias[col];
#pragma unroll
    for (int i = 0; i < 2; i++) {
      int row = m0 + wm + i * 16 + quad * 4;
#pragma unroll
      for (int r = 0; r < 4; r++)
        Cf[(long)(row + r) * 1024 + col] = acc[i][j][r] + bb;
    }
  }
}

// ---------------- split-K x4 flash attention, 4 waves x 32 q-rows -----------
// (unchanged from R14: 44us verified). grid (64,16,2) x 256 thr.
__global__ __launch_bounds__(256, 4) void attn_kernel(
    const u16* __restrict__ Q, const u16* __restrict__ Kb,
    const u16* __restrict__ Vt, u16* __restrict__ Op0, u16* __restrict__ Op3,
    float* __restrict__ lp) {
  __shared__ __attribute__((aligned(16))) u16 Ks[2][32 * 64];  // [key][d], 128B rows
  __shared__ __attribute__((aligned(16))) u16 Vs[2][64 * 32];  // [d][key], 64B rows
  const int t = threadIdx.x, lane = t & 63, w = t >> 6;
  const int l15 = lane & 15, quad = lane >> 4;
  const int xcd = blockIdx.x & 7, rr = blockIdx.x >> 3;
  const int ksp = xcd >> 1, qt = ((xcd & 1) << 3) | rr;
  const int h = blockIdx.y, b = blockIdx.z;
  const int q0 = qt * 128, tok0 = b * 2048, key0 = ksp * 512;
  const u16* Kbase = Kb + (long)tok0 * 1024 + h * 64;
  const u16* Vbase = Vt + (long)(b * 1024 + h * 64) * 2048 + key0;

  // loop-invariant Q fragments (B operand; wave rows q0 + w*32 .. +31)
  bf16x8 aq[2][2];
#pragma unroll
  for (int i = 0; i < 2; i++) {
    long row = tok0 + q0 + w * 32 + i * 16 + l15;
#pragma unroll
    for (int ks = 0; ks < 2; ks++)
      aq[i][ks] = *(const bf16x8*)&Q[row * 1024 + h * 64 + ks * 32 + quad * 8];
  }

  // per-thread staging addrs (256 thr cover 2048-elem tiles in 8-elem chunks).
  // K: chunk ^ ((row>>1)&7); V: chunk ^ ((row>>1)&3) -- swizzle on the GLOBAL
  // chunk so the linear global_load_lds destination stays lane-contiguous.
  const int rk = t >> 3, ck = t & 7;
  const int rv = t >> 2, cv = t & 3;
  const u16* kg = Kbase + (long)(key0 + rk) * 1024 + ((ck ^ ((rk >> 1) & 7)) * 8);
  const u16* vg = Vbase + (long)rv * 2048 + ((cv ^ ((rv >> 1) & 3)) * 8);
  u16* ksd = &Ks[0][t * 8];
  u16* vsd = &Vs[0][t * 8];

  auto STAGE = [&](int tk, int bu) {
    async16(kg + (long)tk * 32768, ksd + bu * 2048);  // +32 rows * 1024
    async16(vg + tk * 32, vsd + bu * 2048);           // +32 key-cols
  };

  STAGE(0, 0);

  float l_st[2] = {};   // per-lane partial over this lane's keys
  f32x4 O[2][4] = {};

  for (int kt = 0; kt < 16; kt++) {
    const int cur = kt & 1;
    __syncthreads();
    if (kt + 1 < 16) STAGE(kt + 1, cur ^ 1);

    // S^T = K Q^T (exp2 domain): A = K rows 2*l15+j, B = aq.
    f32x4 s[2][2] = {};
    __builtin_amdgcn_s_setprio(1);
#pragma unroll
    for (int ks = 0; ks < 2; ks++) {
      bf16x8 bk_[2];
#pragma unroll
      for (int j = 0; j < 2; j++) {
        int rl = 2 * l15 + j;
        bk_[j] = *(const bf16x8*)&Ks[cur][rl * 64 + (((ks * 4 + quad) ^ (l15 & 7))) * 8];
      }
#pragma unroll
      for (int i = 0; i < 2; i++)
#pragma unroll
        for (int j = 0; j < 2; j++)
          s[i][j] = __builtin_amdgcn_mfma_f32_16x16x32_bf16(bk_[j], aq[i][ks], s[i][j], 0, 0, 0);
    }
    __builtin_amdgcn_s_setprio(0);

    // exp2 + in-register pack via cvt_pk: ap[i] word r = keys (8q+2r, 8q+2r+1)
    bf16x8 ap[2];
#pragma unroll
    for (int i = 0; i < 2; i++) {
      union { unsigned uw[4]; bf16x8 v8; } pw;
#pragma unroll
      for (int r = 0; r < 4; r++) {
        float p0 = __builtin_amdgcn_exp2f(s[i][0][r]);
        float p1 = __builtin_amdgcn_exp2f(s[i][1][r]);
        l_st[i] += p0 + p1;
        pw.uw[r] = cvtpk(p0, p1);
      }
      ap[i] = pw.v8;
    }

    // V fragments from LDS; O += P @ V (single K=32 MFMA pass)
    bf16x8 bv_[4];
#pragma unroll
    for (int dj = 0; dj < 4; dj++) {
      int rl = dj * 16 + l15;
      bv_[dj] = *(const bf16x8*)&Vs[cur][rl * 32 + ((quad ^ ((rl >> 1) & 3))) * 8];
    }
    __builtin_amdgcn_s_setprio(1);
#pragma unroll
    for (int i = 0; i < 2; i++)
#pragma unroll
      for (int dj = 0; dj < 4; dj++)
        O[i][dj] = __builtin_amdgcn_mfma_f32_16x16x32_bf16(ap[i], bv_[dj], O[i][dj], 0, 0, 0);
    __builtin_amdgcn_s_setprio(0);
  }

  // epilogue: l reduced across quads; store O (bf16) + l (f32)
  u16* dst = (ksp == 3) ? Op3 : (Op0 + (long)ksp * 4194304);
#pragma unroll
  for (int i = 0; i < 2; i++) {
    float ls = l_st[i];
    ls += __shfl_xor(ls, 16); ls += __shfl_xor(ls, 32);
    if (quad == 0) {
      long qrow = tok0 + q0 + w * 32 + i * 16 + l15;
      lp[ksp * 65536 + (int)qrow * 16 + h] = ls;
    }
#pragma unroll
    for (int r = 0; r < 4; r++) {
      long row = tok0 + q0 + w * 32 + i * 16 + quad * 4 + r;
#pragma unroll
      for (int dj = 0; dj < 4; dj++)
        dst[row * 1024 + h * 64 + dj * 16 + l15] = cvt16(O[i][dj][r]);
    }
  }
}

// ---------------- merge split-K partials: AO = (O0+..+O3)/(l0+..+l3) --------
// AO aliases partial 0 (per-thread read-before-write, 1:1 map -> safe).
__global__ __launch_bounds__(256) void merge_kernel(
    const u16* __restrict__ Op0, const u16* __restrict__ Op3,
    const float* __restrict__ lp, u16* __restrict__ AO) {
  int idx = blockIdx.x * 256 + threadIdx.x;  // 524288 chunks of 8 elems
  int tok = idx >> 7, rem = idx & 127, h = rem >> 3;
  int li = tok * 16 + h;
  float inv = 1.f / (lp[li] + lp[65536 + li] + lp[131072 + li] + lp[196608 + li]);
  union U { uint4 v; u16 us[8]; };
  U a0, a1, a2, a3, uo;
  a0.v = ((const uint4*)Op0)[idx];
  a1.v = ((const uint4*)Op0)[idx + 524288];
  a2.v = ((const uint4*)Op0)[idx + 1048576];
  a3.v = ((const uint4*)Op3)[idx];
#pragma unroll
  for (int j = 0; j < 8; j++) {
    float f0 = __builtin_bit_cast(float, (unsigned)((unsigned)a0.us[j] << 16));
    float f1 = __builtin_bit_cast(float, (unsigned)((unsigned)a1.us[j] << 16));
    float f2 = __builtin_bit_cast(float, (unsigned)((unsigned)a2.us[j] << 16));
    float f3 = __builtin_bit_cast(float, (unsigned)((unsigned)a3.us[j] << 16));
    uo.us[j] = cvt16((f0 + f1 + f2 + f3) * inv);
  }
  ((uint4*)AO)[idx] = uo.v;
}

extern "C" void kernel_launch(void* const* d_in, const int* in_sizes, int n_in,
                              void* d_out, int out_size, void* d_ws, size_t ws_size,
                              hipStream_t stream) {
  const float* q  = (const float*)d_in[0];
  const float* k  = (const float*)d_in[1];
  const float* v  = (const float*)d_in[2];
  const float* Wq = (const float*)d_in[3];
  const float* bq = (const float*)d_in[4];
  const float* Wk = (const float*)d_in[5];
  const float* bk = (const float*)d_in[6];
  const float* Wv = (const float*)d_in[7];
  const float* bv = (const float*)d_in[8];
  const float* Wo = (const float*)d_in[9];
  const float* bo = (const float*)d_in[10];
  const float* gate = (const float*)d_in[11];
  float* out = (float*)d_out;
  char* ws = (char*)d_ws;

  const size_t MB = 1u << 20;
  u16* WQB = (u16*)(ws + 0 * MB);   // WQ|WK|WV|WO contiguous (2MB each)
  u16* WKB = (u16*)(ws + 2 * MB);
  u16* WVB = (u16*)(ws + 4 * MB);
  u16* WOB = (u16*)(ws + 6 * MB);
  u16* QB  = (u16*)(ws + 32 * MB);
  u16* KB  = (u16*)(ws + 40 * MB);
  u16* OPp  = (u16*)(ws + 8 * MB);             // partials 0-2 (24MB)
  u16* OPd3 = (u16*)((char*)d_out + 8 * MB);   // partial 3 in d_out's upper half
  float* LP = (float*)(ws + 0 * MB);           // 1MB partial l (over dead WQB)
  u16* AOB  = (u16*)(ws + 8 * MB);             // == partial 0 (merge self-overwrite)
  u16* VTB  = (u16*)d_out;                     // d_out low 8MB as V^T scratch

  cast_w<<<2048, 256, 0, stream>>>(Wq, Wk, Wv, Wo, WQB, WKB, WVB, WOB);
  gemm_qkv<<<768, 256, 0, stream>>>(q, k, v, WQB, bq, bk, bv, gate, QB, KB, VTB);
  attn_kernel<<<dim3(64, 16, 2), 256, 0, stream>>>(QB, KB, VTB, OPp, OPd3, LP);
  merge_kernel<<<2048, 256, 0, stream>>>(OPp, OPd3, LP, AOB);
  gemm_out<<<1024, 256, 0, stream>>>(AOB, WOB, bo, out);
}